// Round 3
// baseline (2441.384 us; speedup 1.0000x reference)
//
#include <hip/hip_runtime.h>
#include <hip/hip_bf16.h>

// ============================================================================
// EnhancedMathematicalReasoning  (B=4,S=2048,H=2048,E=8, fp32 I/O)
// fp32 via bf16 hi/lo split, 3 MFMA passes. Unified 256x256 GEMM, BK=32,
// 8 waves, 2-phase prefetch dbuf, linear LDS (BK=32 frag reads are
// contiguous 1024B blocks -> conflict-free, no swizzle needed).
// Experts: ONE GEMM over K_eff=8*2048 with per-row Horner/telescoping
// weight folding:  acc *= w[e-1]/w[e] per segment, *w[7] at end.
// ============================================================================

#define MTOT 8192
#define HDIM 2048
#define WMAT ((size_t)HDIM * HDIM)

typedef short bf16x8 __attribute__((ext_vector_type(8)));
typedef float f32x4  __attribute__((ext_vector_type(4)));
typedef unsigned short u16;

__device__ __forceinline__ u16 f2bf(float x) {
    unsigned int u = __float_as_uint(x);
    return (u16)((u + 0x7FFFu + ((u >> 16) & 1u)) >> 16);   // RNE
}
__device__ __forceinline__ float bf2f(u16 u) {
    return __uint_as_float(((unsigned int)u) << 16);
}
__device__ __forceinline__ float gelu_f(float x) {
    return 0.5f * x * (1.0f + erff(x * 0.70710678118654752f));
}

// ---------------------------------------------------------------------------
__global__ void k_split_x(const float* __restrict__ x,
                          u16* __restrict__ hi, u16* __restrict__ lo, long n) {
    long i = ((long)blockIdx.x * blockDim.x + threadIdx.x) * 4;
    long stride = (long)gridDim.x * blockDim.x * 4;
    for (; i < n; i += stride) {
        float4 v = *reinterpret_cast<const float4*>(x + i);
        ushort4 h, l;
        h.x = f2bf(v.x); l.x = f2bf(v.x - bf2f(h.x));
        h.y = f2bf(v.y); l.y = f2bf(v.y - bf2f(h.y));
        h.z = f2bf(v.z); l.z = f2bf(v.z - bf2f(h.z));
        h.w = f2bf(v.w); l.w = f2bf(v.w - bf2f(h.w));
        *reinterpret_cast<ushort4*>(hi + i) = h;
        *reinterpret_cast<ushort4*>(lo + i) = l;
    }
}

// ---------------------------------------------------------------------------
// Split + transpose 11 [K][N] weight mats -> [N][K] hi/lo bf16.
__global__ void k_split_tr(const float* __restrict__ Wd1, const float* __restrict__ We,
                           const float* __restrict__ Wi1, const float* __restrict__ Wi2,
                           u16* __restrict__ th, u16* __restrict__ tl) {
    int z = blockIdx.z;
    const float* src = (z == 0) ? Wd1
                     : (z <= 8) ? (We + (size_t)(z - 1) * WMAT)
                     : (z == 9) ? Wi1 : Wi2;
    size_t dof = (size_t)z * WMAT;
    __shared__ float t[32][33];
    int n0 = blockIdx.x * 32, k0 = blockIdx.y * 32;
    int tx = threadIdx.x & 31, ty = threadIdx.x >> 5;
#pragma unroll
    for (int i = 0; i < 4; ++i) {
        int k = ty + i * 8;
        t[k][tx] = src[(size_t)(k0 + k) * HDIM + n0 + tx];
    }
    __syncthreads();
#pragma unroll
    for (int i = 0; i < 4; ++i) {
        int n = ty + i * 8;
        float v = t[tx][n];
        u16 hv = f2bf(v), lv = f2bf(v - bf2f(hv));
        th[dof + (size_t)(n0 + n) * HDIM + k0 + tx] = hv;
        tl[dof + (size_t)(n0 + n) * HDIM + k0 + tx] = lv;
    }
}

// ---------------------------------------------------------------------------
// Router softmax (fp32 vector GEMV, one wave per row).
__global__ void k_logits(const float* __restrict__ G1, const float* __restrict__ Wd2,
                         const float* __restrict__ bd2, float* __restrict__ opw) {
    int row = blockIdx.x * (blockDim.x >> 6) + (threadIdx.x >> 6);
    int lane = threadIdx.x & 63;
    if (row >= MTOT) return;
    const float* g = G1 + (size_t)row * HDIM;
    float a[8] = {0, 0, 0, 0, 0, 0, 0, 0};
    for (int k = lane; k < HDIM; k += 64) {
        float x = g[k];
        const float* w = Wd2 + (size_t)k * 8;
        float4 w0 = *reinterpret_cast<const float4*>(w);
        float4 w1 = *reinterpret_cast<const float4*>(w + 4);
        a[0] += x * w0.x; a[1] += x * w0.y; a[2] += x * w0.z; a[3] += x * w0.w;
        a[4] += x * w1.x; a[5] += x * w1.y; a[6] += x * w1.z; a[7] += x * w1.w;
    }
#pragma unroll
    for (int off = 32; off > 0; off >>= 1)
#pragma unroll
        for (int e = 0; e < 8; ++e) a[e] += __shfl_xor(a[e], off);
#pragma unroll
    for (int e = 0; e < 8; ++e) a[e] += bd2[e];
    float mx = a[0];
#pragma unroll
    for (int e = 1; e < 8; ++e) mx = fmaxf(mx, a[e]);
    float p[8], s = 0.f;
#pragma unroll
    for (int e = 0; e < 8; ++e) { p[e] = expf(a[e] - mx); s += p[e]; }
    float inv = 1.f / s;
    if (lane < 8) opw[(size_t)row * 8 + lane] = p[lane] * inv;
}

// ---------------------------------------------------------------------------
// Stage one 256x32 bf16 tile (16KB) into LDS, linear, 2 issues/thread.
__device__ __forceinline__ void stage_tile32(const u16* __restrict__ g, size_t row0,
                                             int k0, u16* dst, int tid) {
    int wv = tid >> 6;
#pragma unroll
    for (int i = 0; i < 2; ++i) {
        int slot = i * 512 + tid;              // 16B-slot in tile
        int row = slot >> 2, chunk = slot & 3; // 4 chunks per 64B row
        const u16* src = g + (row0 + (size_t)row) * HDIM + k0 + chunk * 8;
        u16* d = dst + (size_t)((i * 512 + wv * 64) << 3);  // wave-uniform base
        __builtin_amdgcn_global_load_lds((const __attribute__((address_space(1))) void*)src,
                                         (__attribute__((address_space(3))) void*)d,
                                         16, 0, 0);
    }
}

// Unified GEMM: 256x256 tile, BK=32, 8 waves (4x2), wave tile 64x128.
// NE=1: C = A@B^T (+epilogue).  NE=8: experts, K_eff = 8*HDIM, Horner weights.
// EPI: 0 = +bias,gelu -> f32 | 1 = experts (w-fold + w-bias) -> hi/lo
//      2 = +bias,gelu -> hi/lo | 3 = +bias,*mask -> f32
template <int NE, int EPI>
__global__ __launch_bounds__(512, 2)
void k_mm(const u16* __restrict__ Ah, const u16* __restrict__ Al,
          const u16* __restrict__ Bh, const u16* __restrict__ Bl,
          const float* __restrict__ opw, const float* __restrict__ bias,
          const float* __restrict__ mask, float* __restrict__ outF,
          u16* __restrict__ oHi, u16* __restrict__ oLo) {
    __shared__ u16 lsA[2][2][256 * 32];     // [buf][hi/lo][row][k]  64KB
    __shared__ u16 lsB[2][2][256 * 32];     // 64KB
    __shared__ float rat[NE == 8 ? 256 * 8 : 8];

    const int tid = threadIdx.x, lane = tid & 63, wv = tid >> 6;
    const int bx = blockIdx.x & 7, by = blockIdx.x >> 3;   // bx -> XCD (L2 locality)
    const size_t row0 = (size_t)by * 256, col0 = (size_t)bx * 256;
    const int wm = wv >> 1, wn = wv & 1;
    const int lp = lane & 15, lq = lane >> 4;

    if (NE == 8 && tid < 256) {
        const float* w = opw + (row0 + tid) * 8;
        float w8[8];
#pragma unroll
        for (int e = 0; e < 8; ++e) w8[e] = w[e];
#pragma unroll
        for (int e = 0; e < 8; ++e) rat[tid * 8 + e] = w8[(e + 7) & 7] / w8[e];
    }

    stage_tile32(Ah, row0, 0, lsA[0][0], tid);
    stage_tile32(Al, row0, 0, lsA[0][1], tid);
    stage_tile32(Bh, col0, 0, lsB[0][0], tid);
    stage_tile32(Bl, col0, 0, lsB[0][1], tid);
    __syncthreads();

    f32x4 acc[4][8] = {};
    const int NS = NE * (HDIM / 32);
    int ab = 0, bb = 0;

    for (int s = 0; s < NS; ++s) {
        const int e = s & (NE - 1);
        const int s1 = s + 1;
        if (s1 < NS) {                       // prefetch next step's tiles
            const int e1 = s1 & (NE - 1);
            const int k1 = (s1 / NE) * 32;
            if (e1 == 0) {
                stage_tile32(Ah, row0, k1, lsA[ab ^ 1][0], tid);
                stage_tile32(Al, row0, k1, lsA[ab ^ 1][1], tid);
            }
            stage_tile32(Bh + (size_t)e1 * WMAT, col0, k1, lsB[bb ^ 1][0], tid);
            stage_tile32(Bl + (size_t)e1 * WMAT, col0, k1, lsB[bb ^ 1][1], tid);
        }
        if (NE == 8 && s > 0) {              // Horner re-weight (skip s=0: acc=0)
#pragma unroll
            for (int m = 0; m < 4; ++m)
#pragma unroll
                for (int r = 0; r < 4; ++r) {
                    float rv = rat[(wm * 64 + m * 16 + lq * 4 + r) * 8 + e];
#pragma unroll
                    for (int n = 0; n < 8; ++n) acc[m][n][r] *= rv;
                }
        }
        bf16x8 fah[4], fal[4];
#pragma unroll
        for (int m = 0; m < 4; ++m) {
            int rr = wm * 64 + m * 16 + lp;
            fah[m] = *(const bf16x8*)(lsA[ab][0] + rr * 32 + lq * 8);
            fal[m] = *(const bf16x8*)(lsA[ab][1] + rr * 32 + lq * 8);
        }
#pragma unroll
        for (int n = 0; n < 8; ++n) {
            int cr = wn * 128 + n * 16 + lp;
            bf16x8 fbh = *(const bf16x8*)(lsB[bb][0] + cr * 32 + lq * 8);
            bf16x8 fbl = *(const bf16x8*)(lsB[bb][1] + cr * 32 + lq * 8);
#pragma unroll
            for (int m = 0; m < 4; ++m) {
                acc[m][n] = __builtin_amdgcn_mfma_f32_16x16x32_bf16(fah[m], fbh, acc[m][n], 0, 0, 0);
                acc[m][n] = __builtin_amdgcn_mfma_f32_16x16x32_bf16(fah[m], fbl, acc[m][n], 0, 0, 0);
                acc[m][n] = __builtin_amdgcn_mfma_f32_16x16x32_bf16(fal[m], fbh, acc[m][n], 0, 0, 0);
            }
        }
        __syncthreads();
        if (s1 < NS) {
            if ((s1 & (NE - 1)) == 0) ab ^= 1;
            bb ^= 1;
        }
    }

    // ---------------- epilogue ----------------
    if constexpr (EPI == 1) {
        float bev[8][8];                     // be[e][gc] per n-frag
#pragma unroll
        for (int n = 0; n < 8; ++n) {
            size_t gc = col0 + wn * 128 + n * 16 + lp;
#pragma unroll
            for (int e = 0; e < 8; ++e) bev[n][e] = bias[(size_t)e * HDIM + gc];
        }
#pragma unroll
        for (int m = 0; m < 4; ++m)
#pragma unroll
            for (int r = 0; r < 4; ++r) {
                size_t gr = row0 + wm * 64 + m * 16 + lq * 4 + r;
                const float* w = opw + gr * 8;
                float w8[8];
#pragma unroll
                for (int e = 0; e < 8; ++e) w8[e] = w[e];
#pragma unroll
                for (int n = 0; n < 8; ++n) {
                    float bsum = 0.f;
#pragma unroll
                    for (int e = 0; e < 8; ++e) bsum += w8[e] * bev[n][e];
                    float v = acc[m][n][r] * w8[7] + bsum;   // undo Horner basis
                    size_t gc = col0 + wn * 128 + n * 16 + lp;
                    u16 hv = f2bf(v), lv = f2bf(v - bf2f(hv));
                    oHi[gr * HDIM + gc] = hv;
                    oLo[gr * HDIM + gc] = lv;
                }
            }
    } else {
#pragma unroll
        for (int n = 0; n < 8; ++n) {
            size_t gc = col0 + wn * 128 + n * 16 + lp;
            float bv = bias[gc];
#pragma unroll
            for (int m = 0; m < 4; ++m)
#pragma unroll
                for (int r = 0; r < 4; ++r) {
                    size_t gr = row0 + wm * 64 + m * 16 + lq * 4 + r;
                    float v = acc[m][n][r] + bv;
                    if constexpr (EPI == 0) {
                        outF[gr * HDIM + gc] = gelu_f(v);
                    } else if constexpr (EPI == 2) {
                        v = gelu_f(v);
                        u16 hv = f2bf(v), lv = f2bf(v - bf2f(hv));
                        oHi[gr * HDIM + gc] = hv;
                        oLo[gr * HDIM + gc] = lv;
                    } else {
                        outF[gr * HDIM + gc] = v * mask[gr];
                    }
                }
        }
    }
}

// ---------------------------------------------------------------------------
extern "C" void kernel_launch(void* const* d_in, const int* in_sizes, int n_in,
                              void* d_out, int out_size, void* d_ws, size_t ws_size,
                              hipStream_t stream) {
    const float* h    = (const float*)d_in[0];
    const float* amsk = (const float*)d_in[1];
    const float* Wd1  = (const float*)d_in[2];
    const float* bd1  = (const float*)d_in[3];
    const float* Wd2  = (const float*)d_in[4];
    const float* bd2  = (const float*)d_in[5];
    const float* We   = (const float*)d_in[6];
    const float* be   = (const float*)d_in[7];
    const float* Wi1  = (const float*)d_in[8];
    const float* bi1  = (const float*)d_in[9];
    const float* Wi2  = (const float*)d_in[10];
    const float* bi2  = (const float*)d_in[11];
    float* out = (float*)d_out;

    const size_t MB = 1ull << 20;
    char* ws = (char*)d_ws;
    u16* Xh = (u16*)(ws);                    // 32MB   (later reused as Thi)
    u16* Xl = (u16*)(ws + 32 * MB);          // 32MB   (later reused as Tlo)
    u16* Wth = (u16*)(ws + 64 * MB);         // 88MB: 11 transposed hi mats
    u16* Wtl = (u16*)(ws + 152 * MB);        // 88MB: lo mats
    char* rc = ws + 240 * MB;
    float* G1  = (float*)rc;                 // 64MB fp32, later Chi/Clo
    u16*   Chi = (u16*)rc;
    u16*   Clo = (u16*)(rc + 32 * MB);
    float* opw = (float*)(ws + 304 * MB);    // 256KB
    u16* Thi = Xh;
    u16* Tlo = Xl;

    k_split_x<<<4096, 256, 0, stream>>>(h, Xh, Xl, (long)MTOT * HDIM);
    k_split_tr<<<dim3(64, 64, 11), 256, 0, stream>>>(Wd1, We, Wi1, Wi2, Wth, Wtl);

    // G1 = gelu(X @ Wd1 + bd1)
    k_mm<1, 0><<<256, 512, 0, stream>>>(Xh, Xl, Wth, Wtl, nullptr, bd1, nullptr,
                                        G1, nullptr, nullptr);
    // opw = softmax(G1 @ Wd2 + bd2)
    k_logits<<<MTOT / 4, 256, 0, stream>>>(G1, Wd2, bd2, opw);
    // C = sum_e opw .* (X @ We^T + be)  (single GEMM, Horner weights)
    k_mm<8, 1><<<256, 512, 0, stream>>>(Xh, Xl, Wth + WMAT, Wtl + WMAT, opw, be,
                                        nullptr, nullptr, Chi, Clo);
    // T = gelu(C @ Wi1 + bi1)
    k_mm<1, 2><<<256, 512, 0, stream>>>(Chi, Clo, Wth + 9 * WMAT, Wtl + 9 * WMAT,
                                        nullptr, bi1, nullptr, nullptr, Thi, Tlo);
    // out = (T @ Wi2 + bi2) * mask
    k_mm<1, 3><<<256, 512, 0, stream>>>(Thi, Tlo, Wth + 10 * WMAT, Wtl + 10 * WMAT,
                                        nullptr, bi2, amsk, out, nullptr, nullptr);
}